// Round 8
// baseline (243.698 us; speedup 1.0000x reference)
//
#include <hip/hip_runtime.h>

#define DT_C 0.01f

typedef unsigned short u16;
typedef __bf16 bf8 __attribute__((ext_vector_type(8)));
typedef float f32x4 __attribute__((ext_vector_type(4)));

__device__ __forceinline__ u16 f2bf(float f) {
  unsigned u = __float_as_uint(f);
  unsigned r = (u + 0x7FFFu + ((u >> 16) & 1u)) >> 16;
  return (u16)r;
}
__device__ __forceinline__ float bflo(unsigned w) { return __uint_as_float(w << 16); }
__device__ __forceinline__ float bfhi(unsigned w) { return __uint_as_float(w & 0xFFFF0000u); }

// LDS-only barrier: drains lgkmcnt but NOT vmcnt, so in-flight global stores
// don't serialize the scan loop.
__device__ __forceinline__ void wg_barrier() {
  asm volatile("s_waitcnt lgkmcnt(0)" ::: "memory");
  __builtin_amdgcn_s_barrier();
}

// ---------------- kernel 1: context encoder -> h (bf16) ----------------
__global__ __launch_bounds__(512) void k_ctxt(const float* __restrict__ xh,
                                              const float* __restrict__ uh,
                                              const float* __restrict__ Wc,
                                              const float* __restrict__ bc,
                                              u16* __restrict__ h_bf) {
  __shared__ float m[96];
  int b = blockIdx.x, t = threadIdx.x;
  if (t < 96) {
    float s = 0.f;
    if (t < 64) {
      const float* p = xh + (size_t)b * 2048 + t;
      for (int tt = 0; tt < 32; ++tt) s += p[tt * 64];
    } else {
      const float* p = uh + (size_t)b * 1024 + (t - 64);
      for (int tt = 0; tt < 32; ++tt) s += p[tt * 32];
    }
    m[t] = s * (1.0f / 32.0f);
  }
  __syncthreads();
  float acc = bc[t];
  #pragma unroll 8
  for (int s = 0; s < 96; ++s) acc += m[s] * Wc[s * 512 + t];
  h_bf[b * 512 + t] = f2bf(tanhf(acc));
}

// ------- kernel 2: merged head GEMMs. blocks <1024: A_ct (N=65536); else B_mat (N=8192) -------
__global__ __launch_bounds__(256) void k_heads(const u16* __restrict__ hb,
                                               const float* __restrict__ WA,
                                               const float* __restrict__ bA,
                                               const float* __restrict__ WB,
                                               const float* __restrict__ bB,
                                               float* __restrict__ A_ct,
                                               float* __restrict__ B_mat) {
  __shared__ __align__(16) u16 Al[256 * 40];
  __shared__ __align__(16) u16 Bl[64 * 40];
  int t = threadIdx.x;
  const float* W; const float* bias; float* out; int N; int n0;
  if (blockIdx.x < 1024) { W = WA; bias = bA; out = A_ct; N = 65536; n0 = blockIdx.x * 64; }
  else                   { W = WB; bias = bB; out = B_mat; N = 8192; n0 = (blockIdx.x - 1024) * 64; }
  int w = t >> 6, l = t & 63;
  int r16 = l & 15, kb = (l >> 4) * 8;
  f32x4 acc[4][4];
  #pragma unroll
  for (int i = 0; i < 4; ++i)
    #pragma unroll
    for (int j = 0; j < 4; ++j) acc[i][j] = f32x4{0.f, 0.f, 0.f, 0.f};
  for (int kk = 0; kk < 16; ++kk) {
    int k0 = kk * 32;
    {
      int row = t >> 2, kq = t & 3;
      #pragma unroll
      for (int p = 0; p < 4; ++p) {
        int rr = row + 64 * p;
        *(uint4*)(&Al[rr * 40 + kq * 8]) = *(const uint4*)(hb + rr * 512 + k0 + kq * 8);
      }
    }
    {
      int n = t & 63, kp0 = t >> 6;
      #pragma unroll
      for (int r2 = 0; r2 < 4; ++r2) {
        int kp = kp0 * 4 + r2;
        long k = k0 + kp * 2;
        float f0 = W[k * N + n0 + n];
        float f1 = W[(k + 1) * N + n0 + n];
        unsigned pk = ((unsigned)f2bf(f1) << 16) | (unsigned)f2bf(f0);
        *(unsigned*)(&Bl[n * 40 + kp * 2]) = pk;
      }
    }
    __syncthreads();
    bf8 afr[4], bfr[4];
    #pragma unroll
    for (int mf = 0; mf < 4; ++mf)
      afr[mf] = __builtin_bit_cast(bf8, *(const uint4*)(&Al[(w * 64 + mf * 16 + r16) * 40 + kb]));
    #pragma unroll
    for (int nf = 0; nf < 4; ++nf)
      bfr[nf] = __builtin_bit_cast(bf8, *(const uint4*)(&Bl[(nf * 16 + r16) * 40 + kb]));
    #pragma unroll
    for (int mf = 0; mf < 4; ++mf)
      #pragma unroll
      for (int nf = 0; nf < 4; ++nf)
        acc[mf][nf] = __builtin_amdgcn_mfma_f32_16x16x32_bf16(afr[mf], bfr[nf], acc[mf][nf], 0, 0, 0);
    __syncthreads();
  }
  #pragma unroll
  for (int nf = 0; nf < 4; ++nf) {
    int col = n0 + nf * 16 + r16;
    float bv = bias[col];
    #pragma unroll
    for (int mf = 0; mf < 4; ++mf) {
      int row0 = w * 64 + mf * 16 + (l >> 4) * 4;
      #pragma unroll
      for (int r = 0; r < 4; ++r)
        out[(long)(row0 + r) * N + col] = acc[mf][nf][r] + bv;
    }
  }
}

// ---------------- kernel 3: MFMA rollout. 1 block = 1 batch, 4 waves ----------------
// M' = [dt*A | B] (256x288) held as bf16 A-fragments in VGPRs (wave owns 64 rows).
// zext = [z_k ; u_k] bf16 in LDS (576B). acc init = z_old (I term). All 16 MFMA
// columns read the same z, so every lane computes identical z_new (full f32 chain).
__global__ __launch_bounds__(256, 1) void k_scan(const float* __restrict__ Act,
                                                 const float* __restrict__ Bm,
                                                 const float* __restrict__ u_fut,
                                                 const float* __restrict__ x_init,
                                                 const float* __restrict__ We,
                                                 const float* __restrict__ be,
                                                 float* __restrict__ zt) {
  __shared__ __align__(16) u16 zb[2][288];
  __shared__ __align__(16) u16 ustage[128 * 32];
  __shared__ __align__(16) float zf0[256];
  int b = blockIdx.x, t = threadIdx.x;
  int w = t >> 6, l = t & 63;
  int r16 = l & 15, q = l >> 4, kb = q * 8;
  // stage u_fut[b] as bf16 (8KB)
  {
    const float* up = u_fut + (size_t)b * 4096 + t * 16;
    u16 tmp[16];
    #pragma unroll
    for (int e = 0; e < 16; e += 4) {
      float4 v = *(const float4*)(up + e);
      tmp[e] = f2bf(v.x); tmp[e + 1] = f2bf(v.y);
      tmp[e + 2] = f2bf(v.z); tmp[e + 3] = f2bf(v.w);
    }
    *(uint4*)(&ustage[t * 16])     = *(uint4*)(tmp);
    *(uint4*)(&ustage[t * 16 + 8]) = *(uint4*)(tmp + 8);
  }
  // A' fragments: af[rt][kt], rows w*64+rt*16+r16, k-slice kb..kb+8
  bf8 af[4][9];
  {
    const float* A = Act + (size_t)b * 65536;
    const float* B = Bm + (size_t)b * 8192;
    #pragma unroll
    for (int rt = 0; rt < 4; ++rt) {
      int row = w * 64 + rt * 16 + r16;
      const float* rp = A + (size_t)row * 256 + kb;
      #pragma unroll
      for (int kt = 0; kt < 8; ++kt) {
        float4 v0 = *(const float4*)(rp + kt * 32);
        float4 v1 = *(const float4*)(rp + kt * 32 + 4);
        u16 tm[8];
        tm[0] = f2bf(v0.x * DT_C); tm[1] = f2bf(v0.y * DT_C);
        tm[2] = f2bf(v0.z * DT_C); tm[3] = f2bf(v0.w * DT_C);
        tm[4] = f2bf(v1.x * DT_C); tm[5] = f2bf(v1.y * DT_C);
        tm[6] = f2bf(v1.z * DT_C); tm[7] = f2bf(v1.w * DT_C);
        af[rt][kt] = __builtin_bit_cast(bf8, *(uint4*)(tm));
      }
      const float* bp = B + (size_t)row * 32 + kb;
      float4 v0 = *(const float4*)(bp);
      float4 v1 = *(const float4*)(bp + 4);
      u16 tm[8];
      tm[0] = f2bf(v0.x); tm[1] = f2bf(v0.y); tm[2] = f2bf(v0.z); tm[3] = f2bf(v0.w);
      tm[4] = f2bf(v1.x); tm[5] = f2bf(v1.y); tm[6] = f2bf(v1.z); tm[7] = f2bf(v1.w);
      af[rt][8] = __builtin_bit_cast(bf8, *(uint4*)(tm));
    }
  }
  // z0 = We^T x_init + be
  {
    float z = be[t];
    const float* xi = x_init + b * 64;
    #pragma unroll 8
    for (int s = 0; s < 64; ++s) z += xi[s] * We[s * 256 + t];
    zt[(size_t)b * 33024 + t] = z;
    zf0[t] = z;
    zb[0][t] = f2bf(z);
  }
  if (t < 32) zb[0][256 + t] = ustage[t];
  __syncthreads();
  f32x4 zold[4];
  #pragma unroll
  for (int rt = 0; rt < 4; ++rt)
    zold[rt] = *(const f32x4*)(&zf0[w * 64 + rt * 16 + q * 4]);
  float* ztb = zt + (size_t)b * 33024;
  for (int k = 0; k < 128; ++k) {
    const u16* zs = zb[k & 1];
    f32x4 acc[4];
    #pragma unroll
    for (int rt = 0; rt < 4; ++rt) acc[rt] = zold[rt];
    #pragma unroll
    for (int kt = 0; kt < 9; ++kt) {
      bf8 bfv = __builtin_bit_cast(bf8, *(const uint4*)(zs + kt * 32 + kb));
      #pragma unroll
      for (int rt = 0; rt < 4; ++rt)
        acc[rt] = __builtin_amdgcn_mfma_f32_16x16x32_bf16(af[rt][kt], bfv, acc[rt], 0, 0, 0);
    }
    u16* zd = zb[(k + 1) & 1];
    if (r16 == 0) {
      #pragma unroll
      for (int rt = 0; rt < 4; ++rt) {
        int rowb = w * 64 + rt * 16 + q * 4;
        *(f32x4*)(&ztb[(size_t)(k + 1) * 256 + rowb]) = acc[rt];
        unsigned p0 = ((unsigned)f2bf(acc[rt][1]) << 16) | (unsigned)f2bf(acc[rt][0]);
        unsigned p1 = ((unsigned)f2bf(acc[rt][3]) << 16) | (unsigned)f2bf(acc[rt][2]);
        *(uint2*)(&zd[rowb]) = uint2{p0, p1};
      }
    }
    #pragma unroll
    for (int rt = 0; rt < 4; ++rt) zold[rt] = acc[rt];
    if (t < 32 && k < 127) zd[256 + t] = ustage[(k + 1) * 32 + t];
    wg_barrier();
  }
}

// ---- kernel 4: blocks <258: x_traj=z@Wd+bd, z_re=bf16(x)@We+be; blocks >=258: x_gt/z_gt ----
__global__ __launch_bounds__(512) void k_degt(const float* __restrict__ z,
                                              const float* __restrict__ Wd,
                                              const float* __restrict__ bd,
                                              const float* __restrict__ We,
                                              const float* __restrict__ be,
                                              const float* __restrict__ x_init,
                                              const float* __restrict__ x_fut,
                                              float* __restrict__ x_traj,
                                              float* __restrict__ z_re,
                                              float* __restrict__ x_gt,
                                              float* __restrict__ z_gt) {
  __shared__ __align__(16) char sm[55296];
  int t = threadIdx.x;
  int w = t >> 6, l = t & 63, r16 = l & 15, kb = (l >> 4) * 8;
  if (blockIdx.x < 258) {
    u16* Al  = (u16*)(sm);           // [128*40] phase1
    u16* Bl  = (u16*)(sm + 10240);   // [64*40]  phase1
    u16* Xl  = (u16*)(sm);           // [128*72] phase2 x-tile (overlays)
    u16* Bl2 = (u16*)(sm + 18432);   // [256*72] We staged once
    long r0 = (long)blockIdx.x * 128;
    int wm = w >> 2, wn = w & 3;
    {
      int n = t & 255, kh = (t >> 8) * 32;
      #pragma unroll
      for (int kp = 0; kp < 16; ++kp) {
        int k = kh + kp * 2;
        float f0 = We[(size_t)k * 256 + n];
        float f1 = We[(size_t)(k + 1) * 256 + n];
        *(unsigned*)(&Bl2[n * 72 + kh + kp * 2]) = ((unsigned)f2bf(f1) << 16) | (unsigned)f2bf(f0);
      }
    }
    f32x4 acc1[4];
    #pragma unroll
    for (int i = 0; i < 4; ++i) acc1[i] = f32x4{0.f, 0.f, 0.f, 0.f};
    for (int kk = 0; kk < 8; ++kk) {
      int k0 = kk * 32;
      {
        int row = t >> 2, kq = t & 3;
        const float* zs = z + (r0 + row) * 256 + k0 + kq * 8;
        float4 v0 = *(const float4*)(zs);
        float4 v1 = *(const float4*)(zs + 4);
        u16 tmp[8];
        tmp[0] = f2bf(v0.x); tmp[1] = f2bf(v0.y); tmp[2] = f2bf(v0.z); tmp[3] = f2bf(v0.w);
        tmp[4] = f2bf(v1.x); tmp[5] = f2bf(v1.y); tmp[6] = f2bf(v1.z); tmp[7] = f2bf(v1.w);
        *(uint4*)(&Al[row * 40 + kq * 8]) = *(uint4*)(tmp);
      }
      {
        int c = t & 63, kp0 = (t >> 6) * 2;
        #pragma unroll
        for (int r2 = 0; r2 < 2; ++r2) {
          int kp = kp0 + r2;
          int k = k0 + kp * 2;
          float f0 = Wd[(size_t)k * 64 + c];
          float f1 = Wd[(size_t)(k + 1) * 64 + c];
          *(unsigned*)(&Bl[c * 40 + kp * 2]) = ((unsigned)f2bf(f1) << 16) | (unsigned)f2bf(f0);
        }
      }
      __syncthreads();
      bf8 af[4];
      #pragma unroll
      for (int mf = 0; mf < 4; ++mf)
        af[mf] = __builtin_bit_cast(bf8, *(const uint4*)(&Al[(wm * 64 + mf * 16 + r16) * 40 + kb]));
      bf8 bf1 = __builtin_bit_cast(bf8, *(const uint4*)(&Bl[(wn * 16 + r16) * 40 + kb]));
      #pragma unroll
      for (int mf = 0; mf < 4; ++mf)
        acc1[mf] = __builtin_amdgcn_mfma_f32_16x16x32_bf16(af[mf], bf1, acc1[mf], 0, 0, 0);
      __syncthreads();
    }
    {
      int c = wn * 16 + r16;
      float bv = bd[c];
      #pragma unroll
      for (int mf = 0; mf < 4; ++mf) {
        int rowb = wm * 64 + mf * 16 + (l >> 4) * 4;
        #pragma unroll
        for (int r = 0; r < 4; ++r) {
          float val = acc1[mf][r] + bv;
          x_traj[(r0 + rowb + r) * 64 + c] = val;
          Xl[(rowb + r) * 72 + c] = f2bf(val);
        }
      }
    }
    __syncthreads();
    f32x4 acc2[4][4];
    #pragma unroll
    for (int i = 0; i < 4; ++i)
      #pragma unroll
      for (int j = 0; j < 4; ++j) acc2[i][j] = f32x4{0.f, 0.f, 0.f, 0.f};
    #pragma unroll
    for (int kk = 0; kk < 2; ++kk) {
      int k0 = kk * 32;
      bf8 af[4], bfv[4];
      #pragma unroll
      for (int mf = 0; mf < 4; ++mf)
        af[mf] = __builtin_bit_cast(bf8, *(const uint4*)(&Xl[(wm * 64 + mf * 16 + r16) * 72 + k0 + kb]));
      #pragma unroll
      for (int nf = 0; nf < 4; ++nf)
        bfv[nf] = __builtin_bit_cast(bf8, *(const uint4*)(&Bl2[(wn * 64 + nf * 16 + r16) * 72 + k0 + kb]));
      #pragma unroll
      for (int mf = 0; mf < 4; ++mf)
        #pragma unroll
        for (int nf = 0; nf < 4; ++nf)
          acc2[mf][nf] = __builtin_amdgcn_mfma_f32_16x16x32_bf16(af[mf], bfv[nf], acc2[mf][nf], 0, 0, 0);
    }
    #pragma unroll
    for (int nf = 0; nf < 4; ++nf) {
      int c = wn * 64 + nf * 16 + r16;
      float bv = be[c];
      #pragma unroll
      for (int mf = 0; mf < 4; ++mf) {
        long row0 = r0 + wm * 64 + mf * 16 + (l >> 4) * 4;
        #pragma unroll
        for (int r = 0; r < 4; ++r)
          z_re[(row0 + r) * 256 + c] = acc2[mf][nf][r] + bv;
      }
    }
  } else {
    // ---------------- gt branch: assemble x_gt, z_gt = x_gt @ We + be ----------------
    u16* Al = (u16*)(sm);            // [128*40]
    u16* Bl = (u16*)(sm + 10240);    // [256*40]
    long r0 = (long)(blockIdx.x - 258) * 128;
    int wm = w >> 2, wn = w & 3;
    f32x4 acc[4][4];
    #pragma unroll
    for (int i = 0; i < 4; ++i)
      #pragma unroll
      for (int j = 0; j < 4; ++j) acc[i][j] = f32x4{0.f, 0.f, 0.f, 0.f};
    for (int kk = 0; kk < 2; ++kk) {
      int k0 = kk * 32;
      {
        int row = t >> 2, kq = t & 3;
        long gr = r0 + row;
        unsigned bb = (unsigned)gr / 129u;
        unsigned rr = (unsigned)gr - bb * 129u;
        const float* src = (rr == 0) ? (x_init + (size_t)bb * 64)
                                     : (x_fut + ((size_t)bb * 128 + (rr - 1)) * 64);
        float4 v0 = *(const float4*)(src + k0 + kq * 8);
        float4 v1 = *(const float4*)(src + k0 + kq * 8 + 4);
        *(float4*)(&x_gt[gr * 64 + k0 + kq * 8]) = v0;
        *(float4*)(&x_gt[gr * 64 + k0 + kq * 8 + 4]) = v1;
        u16 tmp[8];
        tmp[0] = f2bf(v0.x); tmp[1] = f2bf(v0.y); tmp[2] = f2bf(v0.z); tmp[3] = f2bf(v0.w);
        tmp[4] = f2bf(v1.x); tmp[5] = f2bf(v1.y); tmp[6] = f2bf(v1.z); tmp[7] = f2bf(v1.w);
        *(uint4*)(&Al[row * 40 + kq * 8]) = *(uint4*)(tmp);
      }
      {
        int n = t & 255, kh = (t >> 8) * 16;
        #pragma unroll
        for (int kp = 0; kp < 8; ++kp) {
          int k = k0 + kh + kp * 2;
          float f0 = We[(size_t)k * 256 + n];
          float f1 = We[(size_t)(k + 1) * 256 + n];
          *(unsigned*)(&Bl[n * 40 + kh + kp * 2]) = ((unsigned)f2bf(f1) << 16) | (unsigned)f2bf(f0);
        }
      }
      __syncthreads();
      bf8 af[4], bfv[4];
      #pragma unroll
      for (int mf = 0; mf < 4; ++mf)
        af[mf] = __builtin_bit_cast(bf8, *(const uint4*)(&Al[(wm * 64 + mf * 16 + r16) * 40 + kb]));
      #pragma unroll
      for (int nf = 0; nf < 4; ++nf)
        bfv[nf] = __builtin_bit_cast(bf8, *(const uint4*)(&Bl[(wn * 64 + nf * 16 + r16) * 40 + kb]));
      #pragma unroll
      for (int mf = 0; mf < 4; ++mf)
        #pragma unroll
        for (int nf = 0; nf < 4; ++nf)
          acc[mf][nf] = __builtin_amdgcn_mfma_f32_16x16x32_bf16(af[mf], bfv[nf], acc[mf][nf], 0, 0, 0);
      __syncthreads();
    }
    #pragma unroll
    for (int nf = 0; nf < 4; ++nf) {
      int c = wn * 64 + nf * 16 + r16;
      float bv = be[c];
      #pragma unroll
      for (int mf = 0; mf < 4; ++mf) {
        long row0 = r0 + wm * 64 + mf * 16 + (l >> 4) * 4;
        #pragma unroll
        for (int r = 0; r < 4; ++r)
          z_gt[(row0 + r) * 256 + c] = acc[mf][nf][r] + bv;
      }
    }
  }
}

extern "C" void kernel_launch(void* const* d_in, const int* in_sizes, int n_in,
                              void* d_out, int out_size, void* d_ws, size_t ws_size,
                              hipStream_t stream) {
  const float* xh     = (const float*)d_in[0];
  const float* uh     = (const float*)d_in[1];
  const float* x_init = (const float*)d_in[2];
  const float* x_fut  = (const float*)d_in[3];
  const float* u_fut  = (const float*)d_in[4];
  const float* Wc = (const float*)d_in[6];
  const float* bc = (const float*)d_in[7];
  const float* WA = (const float*)d_in[8];
  const float* bA = (const float*)d_in[9];
  const float* WB = (const float*)d_in[10];
  const float* bB = (const float*)d_in[11];
  const float* We = (const float*)d_in[12];
  const float* be = (const float*)d_in[13];
  const float* Wd = (const float*)d_in[14];
  const float* bd = (const float*)d_in[15];

  float* out    = (float*)d_out;
  float* z_traj = out;                 // [256,129,256]
  float* x_traj = out + 8454144;       // [256,129,64]
  float* A_ct   = out + 10567680;      // [256,256,256]
  float* B_mat  = out + 27344896;      // [256,256,32]
  float* z_re   = out + 29442048;      // [256,129,256]
  float* x_gt   = out + 37896192;      // [256,129,64]
  float* z_gt   = out + 40009728;      // [256,129,256]

  u16* h_bf = (u16*)d_ws;              // 256KB

  hipLaunchKernelGGL(k_ctxt,  dim3(256),  dim3(512), 0, stream, xh, uh, Wc, bc, h_bf);
  hipLaunchKernelGGL(k_heads, dim3(1152), dim3(256), 0, stream, h_bf, WA, bA, WB, bB, A_ct, B_mat);
  hipLaunchKernelGGL(k_scan,  dim3(256),  dim3(256), 0, stream, A_ct, B_mat, u_fut, x_init, We, be, z_traj);
  hipLaunchKernelGGL(k_degt,  dim3(516),  dim3(512), 0, stream, z_traj, Wd, bd, We, be,
                     x_init, x_fut, x_traj, z_re, x_gt, z_gt);
}

// Round 9
// 203.774 us; speedup vs baseline: 1.1959x; 1.1959x over previous
//
#include <hip/hip_runtime.h>

#define DT_C 0.01f

typedef unsigned short u16;
typedef __bf16 bf8 __attribute__((ext_vector_type(8)));
typedef float f32x4 __attribute__((ext_vector_type(4)));

__device__ __forceinline__ u16 f2bf(float f) {
  unsigned u = __float_as_uint(f);
  unsigned r = (u + 0x7FFFu + ((u >> 16) & 1u)) >> 16;
  return (u16)r;
}

// LDS-only barrier: drains lgkmcnt but NOT vmcnt, so in-flight global stores
// don't serialize the scan loop.
__device__ __forceinline__ void wg_barrier() {
  asm volatile("s_waitcnt lgkmcnt(0)" ::: "memory");
  __builtin_amdgcn_s_barrier();
}

// ---------------- kernel 1: context encoder -> h (bf16) ----------------
__global__ __launch_bounds__(512) void k_ctxt(const float* __restrict__ xh,
                                              const float* __restrict__ uh,
                                              const float* __restrict__ Wc,
                                              const float* __restrict__ bc,
                                              u16* __restrict__ h_bf) {
  __shared__ float m[96];
  int b = blockIdx.x, t = threadIdx.x;
  if (t < 96) {
    float s = 0.f;
    if (t < 64) {
      const float* p = xh + (size_t)b * 2048 + t;
      for (int tt = 0; tt < 32; ++tt) s += p[tt * 64];
    } else {
      const float* p = uh + (size_t)b * 1024 + (t - 64);
      for (int tt = 0; tt < 32; ++tt) s += p[tt * 32];
    }
    m[t] = s * (1.0f / 32.0f);
  }
  __syncthreads();
  float acc = bc[t];
  #pragma unroll 8
  for (int s = 0; s < 96; ++s) acc += m[s] * Wc[s * 512 + t];
  h_bf[b * 512 + t] = f2bf(tanhf(acc));
}

// ------- kernel 2: merged head GEMMs. blocks <1024: A_ct (N=65536); else B_mat (N=8192) -------
__global__ __launch_bounds__(256) void k_heads(const u16* __restrict__ hb,
                                               const float* __restrict__ WA,
                                               const float* __restrict__ bA,
                                               const float* __restrict__ WB,
                                               const float* __restrict__ bB,
                                               float* __restrict__ A_ct,
                                               float* __restrict__ B_mat) {
  __shared__ __align__(16) u16 Al[256 * 40];
  __shared__ __align__(16) u16 Bl[64 * 40];
  int t = threadIdx.x;
  const float* W; const float* bias; float* out; int N; int n0;
  if (blockIdx.x < 1024) { W = WA; bias = bA; out = A_ct; N = 65536; n0 = blockIdx.x * 64; }
  else                   { W = WB; bias = bB; out = B_mat; N = 8192; n0 = (blockIdx.x - 1024) * 64; }
  int w = t >> 6, l = t & 63;
  int r16 = l & 15, kb = (l >> 4) * 8;
  f32x4 acc[4][4];
  #pragma unroll
  for (int i = 0; i < 4; ++i)
    #pragma unroll
    for (int j = 0; j < 4; ++j) acc[i][j] = f32x4{0.f, 0.f, 0.f, 0.f};
  for (int kk = 0; kk < 16; ++kk) {
    int k0 = kk * 32;
    {
      int row = t >> 2, kq = t & 3;
      #pragma unroll
      for (int p = 0; p < 4; ++p) {
        int rr = row + 64 * p;
        *(uint4*)(&Al[rr * 40 + kq * 8]) = *(const uint4*)(hb + rr * 512 + k0 + kq * 8);
      }
    }
    {
      int n = t & 63, kp0 = t >> 6;
      #pragma unroll
      for (int r2 = 0; r2 < 4; ++r2) {
        int kp = kp0 * 4 + r2;
        long k = k0 + kp * 2;
        float f0 = W[k * N + n0 + n];
        float f1 = W[(k + 1) * N + n0 + n];
        unsigned pk = ((unsigned)f2bf(f1) << 16) | (unsigned)f2bf(f0);
        *(unsigned*)(&Bl[n * 40 + kp * 2]) = pk;
      }
    }
    __syncthreads();
    bf8 afr[4], bfr[4];
    #pragma unroll
    for (int mf = 0; mf < 4; ++mf)
      afr[mf] = __builtin_bit_cast(bf8, *(const uint4*)(&Al[(w * 64 + mf * 16 + r16) * 40 + kb]));
    #pragma unroll
    for (int nf = 0; nf < 4; ++nf)
      bfr[nf] = __builtin_bit_cast(bf8, *(const uint4*)(&Bl[(nf * 16 + r16) * 40 + kb]));
    #pragma unroll
    for (int mf = 0; mf < 4; ++mf)
      #pragma unroll
      for (int nf = 0; nf < 4; ++nf)
        acc[mf][nf] = __builtin_amdgcn_mfma_f32_16x16x32_bf16(afr[mf], bfr[nf], acc[mf][nf], 0, 0, 0);
    __syncthreads();
  }
  #pragma unroll
  for (int nf = 0; nf < 4; ++nf) {
    int col = n0 + nf * 16 + r16;
    float bv = bias[col];
    #pragma unroll
    for (int mf = 0; mf < 4; ++mf) {
      int row0 = w * 64 + mf * 16 + (l >> 4) * 4;
      #pragma unroll
      for (int r = 0; r < 4; ++r)
        out[(long)(row0 + r) * N + col] = acc[mf][nf][r] + bv;
    }
  }
}

// ---------------- kernel 3: MFMA rollout. 1 block = 1 batch, 8 waves (2/SIMD) ----------------
// Wave owns 32 rows (2 rt tiles). M' = [dt*A | B] bf16 fragments in VGPRs.
// z_k bf16 in LDS (512B dbuf); u_k read directly from ustage (no per-step copy).
// acc init = z_old (I term); all 16 MFMA columns compute identical z_new.
__global__ __launch_bounds__(512, 2) void k_scan(const float* __restrict__ Act,
                                                 const float* __restrict__ Bm,
                                                 const float* __restrict__ u_fut,
                                                 const float* __restrict__ x_init,
                                                 const float* __restrict__ We,
                                                 const float* __restrict__ be,
                                                 float* __restrict__ zt) {
  __shared__ __align__(16) u16 zb[2][256];
  __shared__ __align__(16) u16 ustage[128 * 32];
  __shared__ __align__(16) float zf0[256];
  int b = blockIdx.x, t = threadIdx.x;
  int w = t >> 6, l = t & 63;
  int r16 = l & 15, q = l >> 4, kb = q * 8;
  // stage u_fut[b] as bf16 (8KB): 512 threads x 8 f32
  {
    const float* up = u_fut + (size_t)b * 4096 + t * 8;
    float4 v0 = *(const float4*)(up);
    float4 v1 = *(const float4*)(up + 4);
    u16 tmp[8];
    tmp[0] = f2bf(v0.x); tmp[1] = f2bf(v0.y); tmp[2] = f2bf(v0.z); tmp[3] = f2bf(v0.w);
    tmp[4] = f2bf(v1.x); tmp[5] = f2bf(v1.y); tmp[6] = f2bf(v1.z); tmp[7] = f2bf(v1.w);
    *(uint4*)(&ustage[t * 8]) = *(uint4*)(tmp);
  }
  // A' fragments: af[rt][kt], rows w*32+rt*16+r16, k-slice kb..kb+8
  bf8 af[2][9];
  {
    const float* A = Act + (size_t)b * 65536;
    const float* B = Bm + (size_t)b * 8192;
    #pragma unroll
    for (int rt = 0; rt < 2; ++rt) {
      int row = w * 32 + rt * 16 + r16;
      const float* rp = A + (size_t)row * 256 + kb;
      #pragma unroll
      for (int kt = 0; kt < 8; ++kt) {
        float4 v0 = *(const float4*)(rp + kt * 32);
        float4 v1 = *(const float4*)(rp + kt * 32 + 4);
        u16 tm[8];
        tm[0] = f2bf(v0.x * DT_C); tm[1] = f2bf(v0.y * DT_C);
        tm[2] = f2bf(v0.z * DT_C); tm[3] = f2bf(v0.w * DT_C);
        tm[4] = f2bf(v1.x * DT_C); tm[5] = f2bf(v1.y * DT_C);
        tm[6] = f2bf(v1.z * DT_C); tm[7] = f2bf(v1.w * DT_C);
        af[rt][kt] = __builtin_bit_cast(bf8, *(uint4*)(tm));
      }
      const float* bp = B + (size_t)row * 32 + kb;
      float4 v0 = *(const float4*)(bp);
      float4 v1 = *(const float4*)(bp + 4);
      u16 tm[8];
      tm[0] = f2bf(v0.x); tm[1] = f2bf(v0.y); tm[2] = f2bf(v0.z); tm[3] = f2bf(v0.w);
      tm[4] = f2bf(v1.x); tm[5] = f2bf(v1.y); tm[6] = f2bf(v1.z); tm[7] = f2bf(v1.w);
      af[rt][8] = __builtin_bit_cast(bf8, *(uint4*)(tm));
    }
  }
  // z0 = We^T x_init + be
  if (t < 256) {
    float z = be[t];
    const float* xi = x_init + b * 64;
    #pragma unroll 8
    for (int s = 0; s < 64; ++s) z += xi[s] * We[s * 256 + t];
    zt[(size_t)b * 33024 + t] = z;
    zf0[t] = z;
    zb[0][t] = f2bf(z);
  }
  __syncthreads();
  f32x4 zold[2];
  #pragma unroll
  for (int rt = 0; rt < 2; ++rt)
    zold[rt] = *(const f32x4*)(&zf0[w * 32 + rt * 16 + q * 4]);
  float* ztb = zt + (size_t)b * 33024;
  for (int k = 0; k < 128; ++k) {
    const u16* zs = zb[k & 1];
    f32x4 acc[2];
    #pragma unroll
    for (int rt = 0; rt < 2; ++rt) acc[rt] = zold[rt];
    #pragma unroll
    for (int kt = 0; kt < 8; ++kt) {
      bf8 bfv = __builtin_bit_cast(bf8, *(const uint4*)(zs + kt * 32 + kb));
      #pragma unroll
      for (int rt = 0; rt < 2; ++rt)
        acc[rt] = __builtin_amdgcn_mfma_f32_16x16x32_bf16(af[rt][kt], bfv, acc[rt], 0, 0, 0);
    }
    {  // u-term: B fragment straight from ustage (no per-step copy)
      bf8 bfu = __builtin_bit_cast(bf8, *(const uint4*)(ustage + k * 32 + kb));
      #pragma unroll
      for (int rt = 0; rt < 2; ++rt)
        acc[rt] = __builtin_amdgcn_mfma_f32_16x16x32_bf16(af[rt][8], bfu, acc[rt], 0, 0, 0);
    }
    u16* zd = zb[(k + 1) & 1];
    if (r16 == 0) {
      #pragma unroll
      for (int rt = 0; rt < 2; ++rt) {
        int rowb = w * 32 + rt * 16 + q * 4;
        *(f32x4*)(&ztb[(size_t)(k + 1) * 256 + rowb]) = acc[rt];
        unsigned p0 = ((unsigned)f2bf(acc[rt][1]) << 16) | (unsigned)f2bf(acc[rt][0]);
        unsigned p1 = ((unsigned)f2bf(acc[rt][3]) << 16) | (unsigned)f2bf(acc[rt][2]);
        *(uint2*)(&zd[rowb]) = uint2{p0, p1};
      }
    }
    #pragma unroll
    for (int rt = 0; rt < 2; ++rt) zold[rt] = acc[rt];
    wg_barrier();
  }
}

// ---- kernel 4: blocks <258: x_traj=z@Wd+bd, z_re=bf16(x)@We+be; blocks >=258: x_gt/z_gt ----
__global__ __launch_bounds__(512) void k_degt(const float* __restrict__ z,
                                              const float* __restrict__ Wd,
                                              const float* __restrict__ bd,
                                              const float* __restrict__ We,
                                              const float* __restrict__ be,
                                              const float* __restrict__ x_init,
                                              const float* __restrict__ x_fut,
                                              float* __restrict__ x_traj,
                                              float* __restrict__ z_re,
                                              float* __restrict__ x_gt,
                                              float* __restrict__ z_gt) {
  __shared__ __align__(16) char sm[55296];
  int t = threadIdx.x;
  int w = t >> 6, l = t & 63, r16 = l & 15, kb = (l >> 4) * 8;
  if (blockIdx.x < 258) {
    u16* Al  = (u16*)(sm);           // [128*40] phase1
    u16* Bl  = (u16*)(sm + 10240);   // [64*40]  phase1
    u16* Xl  = (u16*)(sm);           // [128*72] phase2 x-tile (overlays)
    u16* Bl2 = (u16*)(sm + 18432);   // [256*72] We staged once
    long r0 = (long)blockIdx.x * 128;
    int wm = w >> 2, wn = w & 3;
    {
      int n = t & 255, kh = (t >> 8) * 32;
      #pragma unroll
      for (int kp = 0; kp < 16; ++kp) {
        int k = kh + kp * 2;
        float f0 = We[(size_t)k * 256 + n];
        float f1 = We[(size_t)(k + 1) * 256 + n];
        *(unsigned*)(&Bl2[n * 72 + kh + kp * 2]) = ((unsigned)f2bf(f1) << 16) | (unsigned)f2bf(f0);
      }
    }
    f32x4 acc1[4];
    #pragma unroll
    for (int i = 0; i < 4; ++i) acc1[i] = f32x4{0.f, 0.f, 0.f, 0.f};
    for (int kk = 0; kk < 8; ++kk) {
      int k0 = kk * 32;
      {
        int row = t >> 2, kq = t & 3;
        const float* zs = z + (r0 + row) * 256 + k0 + kq * 8;
        float4 v0 = *(const float4*)(zs);
        float4 v1 = *(const float4*)(zs + 4);
        u16 tmp[8];
        tmp[0] = f2bf(v0.x); tmp[1] = f2bf(v0.y); tmp[2] = f2bf(v0.z); tmp[3] = f2bf(v0.w);
        tmp[4] = f2bf(v1.x); tmp[5] = f2bf(v1.y); tmp[6] = f2bf(v1.z); tmp[7] = f2bf(v1.w);
        *(uint4*)(&Al[row * 40 + kq * 8]) = *(uint4*)(tmp);
      }
      {
        int c = t & 63, kp0 = (t >> 6) * 2;
        #pragma unroll
        for (int r2 = 0; r2 < 2; ++r2) {
          int kp = kp0 + r2;
          int k = k0 + kp * 2;
          float f0 = Wd[(size_t)k * 64 + c];
          float f1 = Wd[(size_t)(k + 1) * 64 + c];
          *(unsigned*)(&Bl[c * 40 + kp * 2]) = ((unsigned)f2bf(f1) << 16) | (unsigned)f2bf(f0);
        }
      }
      __syncthreads();
      bf8 af[4];
      #pragma unroll
      for (int mf = 0; mf < 4; ++mf)
        af[mf] = __builtin_bit_cast(bf8, *(const uint4*)(&Al[(wm * 64 + mf * 16 + r16) * 40 + kb]));
      bf8 bf1 = __builtin_bit_cast(bf8, *(const uint4*)(&Bl[(wn * 16 + r16) * 40 + kb]));
      #pragma unroll
      for (int mf = 0; mf < 4; ++mf)
        acc1[mf] = __builtin_amdgcn_mfma_f32_16x16x32_bf16(af[mf], bf1, acc1[mf], 0, 0, 0);
      __syncthreads();
    }
    {
      int c = wn * 16 + r16;
      float bv = bd[c];
      #pragma unroll
      for (int mf = 0; mf < 4; ++mf) {
        int rowb = wm * 64 + mf * 16 + (l >> 4) * 4;
        #pragma unroll
        for (int r = 0; r < 4; ++r) {
          float val = acc1[mf][r] + bv;
          x_traj[(r0 + rowb + r) * 64 + c] = val;
          Xl[(rowb + r) * 72 + c] = f2bf(val);
        }
      }
    }
    __syncthreads();
    f32x4 acc2[4][4];
    #pragma unroll
    for (int i = 0; i < 4; ++i)
      #pragma unroll
      for (int j = 0; j < 4; ++j) acc2[i][j] = f32x4{0.f, 0.f, 0.f, 0.f};
    #pragma unroll
    for (int kk = 0; kk < 2; ++kk) {
      int k0 = kk * 32;
      bf8 af[4], bfv[4];
      #pragma unroll
      for (int mf = 0; mf < 4; ++mf)
        af[mf] = __builtin_bit_cast(bf8, *(const uint4*)(&Xl[(wm * 64 + mf * 16 + r16) * 72 + k0 + kb]));
      #pragma unroll
      for (int nf = 0; nf < 4; ++nf)
        bfv[nf] = __builtin_bit_cast(bf8, *(const uint4*)(&Bl2[(wn * 64 + nf * 16 + r16) * 72 + k0 + kb]));
      #pragma unroll
      for (int mf = 0; mf < 4; ++mf)
        #pragma unroll
        for (int nf = 0; nf < 4; ++nf)
          acc2[mf][nf] = __builtin_amdgcn_mfma_f32_16x16x32_bf16(af[mf], bfv[nf], acc2[mf][nf], 0, 0, 0);
    }
    #pragma unroll
    for (int nf = 0; nf < 4; ++nf) {
      int c = wn * 64 + nf * 16 + r16;
      float bv = be[c];
      #pragma unroll
      for (int mf = 0; mf < 4; ++mf) {
        long row0 = r0 + wm * 64 + mf * 16 + (l >> 4) * 4;
        #pragma unroll
        for (int r = 0; r < 4; ++r)
          z_re[(row0 + r) * 256 + c] = acc2[mf][nf][r] + bv;
      }
    }
  } else {
    // ---------------- gt branch: assemble x_gt, z_gt = x_gt @ We + be ----------------
    u16* Al = (u16*)(sm);            // [128*40]
    u16* Bl = (u16*)(sm + 10240);    // [256*40]
    long r0 = (long)(blockIdx.x - 258) * 128;
    int wm = w >> 2, wn = w & 3;
    f32x4 acc[4][4];
    #pragma unroll
    for (int i = 0; i < 4; ++i)
      #pragma unroll
      for (int j = 0; j < 4; ++j) acc[i][j] = f32x4{0.f, 0.f, 0.f, 0.f};
    for (int kk = 0; kk < 2; ++kk) {
      int k0 = kk * 32;
      {
        int row = t >> 2, kq = t & 3;
        long gr = r0 + row;
        unsigned bb = (unsigned)gr / 129u;
        unsigned rr = (unsigned)gr - bb * 129u;
        const float* src = (rr == 0) ? (x_init + (size_t)bb * 64)
                                     : (x_fut + ((size_t)bb * 128 + (rr - 1)) * 64);
        float4 v0 = *(const float4*)(src + k0 + kq * 8);
        float4 v1 = *(const float4*)(src + k0 + kq * 8 + 4);
        *(float4*)(&x_gt[gr * 64 + k0 + kq * 8]) = v0;
        *(float4*)(&x_gt[gr * 64 + k0 + kq * 8 + 4]) = v1;
        u16 tmp[8];
        tmp[0] = f2bf(v0.x); tmp[1] = f2bf(v0.y); tmp[2] = f2bf(v0.z); tmp[3] = f2bf(v0.w);
        tmp[4] = f2bf(v1.x); tmp[5] = f2bf(v1.y); tmp[6] = f2bf(v1.z); tmp[7] = f2bf(v1.w);
        *(uint4*)(&Al[row * 40 + kq * 8]) = *(uint4*)(tmp);
      }
      {
        int n = t & 255, kh = (t >> 8) * 16;
        #pragma unroll
        for (int kp = 0; kp < 8; ++kp) {
          int k = k0 + kh + kp * 2;
          float f0 = We[(size_t)k * 256 + n];
          float f1 = We[(size_t)(k + 1) * 256 + n];
          *(unsigned*)(&Bl[n * 40 + kh + kp * 2]) = ((unsigned)f2bf(f1) << 16) | (unsigned)f2bf(f0);
        }
      }
      __syncthreads();
      bf8 af[4], bfv[4];
      #pragma unroll
      for (int mf = 0; mf < 4; ++mf)
        af[mf] = __builtin_bit_cast(bf8, *(const uint4*)(&Al[(wm * 64 + mf * 16 + r16) * 40 + kb]));
      #pragma unroll
      for (int nf = 0; nf < 4; ++nf)
        bfv[nf] = __builtin_bit_cast(bf8, *(const uint4*)(&Bl[(wn * 64 + nf * 16 + r16) * 40 + kb]));
      #pragma unroll
      for (int mf = 0; mf < 4; ++mf)
        #pragma unroll
        for (int nf = 0; nf < 4; ++nf)
          acc[mf][nf] = __builtin_amdgcn_mfma_f32_16x16x32_bf16(af[mf], bfv[nf], acc[mf][nf], 0, 0, 0);
      __syncthreads();
    }
    #pragma unroll
    for (int nf = 0; nf < 4; ++nf) {
      int c = wn * 64 + nf * 16 + r16;
      float bv = be[c];
      #pragma unroll
      for (int mf = 0; mf < 4; ++mf) {
        long row0 = r0 + wm * 64 + mf * 16 + (l >> 4) * 4;
        #pragma unroll
        for (int r = 0; r < 4; ++r)
          z_gt[(row0 + r) * 256 + c] = acc[mf][nf][r] + bv;
      }
    }
  }
}

extern "C" void kernel_launch(void* const* d_in, const int* in_sizes, int n_in,
                              void* d_out, int out_size, void* d_ws, size_t ws_size,
                              hipStream_t stream) {
  const float* xh     = (const float*)d_in[0];
  const float* uh     = (const float*)d_in[1];
  const float* x_init = (const float*)d_in[2];
  const float* x_fut  = (const float*)d_in[3];
  const float* u_fut  = (const float*)d_in[4];
  const float* Wc = (const float*)d_in[6];
  const float* bc = (const float*)d_in[7];
  const float* WA = (const float*)d_in[8];
  const float* bA = (const float*)d_in[9];
  const float* WB = (const float*)d_in[10];
  const float* bB = (const float*)d_in[11];
  const float* We = (const float*)d_in[12];
  const float* be = (const float*)d_in[13];
  const float* Wd = (const float*)d_in[14];
  const float* bd = (const float*)d_in[15];

  float* out    = (float*)d_out;
  float* z_traj = out;                 // [256,129,256]
  float* x_traj = out + 8454144;       // [256,129,64]
  float* A_ct   = out + 10567680;      // [256,256,256]
  float* B_mat  = out + 27344896;      // [256,256,32]
  float* z_re   = out + 29442048;      // [256,129,256]
  float* x_gt   = out + 37896192;      // [256,129,64]
  float* z_gt   = out + 40009728;      // [256,129,256]

  u16* h_bf = (u16*)d_ws;              // 256KB

  hipLaunchKernelGGL(k_ctxt,  dim3(256),  dim3(512), 0, stream, xh, uh, Wc, bc, h_bf);
  hipLaunchKernelGGL(k_heads, dim3(1152), dim3(256), 0, stream, h_bf, WA, bA, WB, bB, A_ct, B_mat);
  hipLaunchKernelGGL(k_scan,  dim3(256),  dim3(512), 0, stream, A_ct, B_mat, u_fut, x_init, We, be, z_traj);
  hipLaunchKernelGGL(k_degt,  dim3(516),  dim3(512), 0, stream, z_traj, Wd, bd, We, be,
                     x_init, x_fut, x_traj, z_re, x_gt, z_gt);
}